// Round 3
// baseline (6554.499 us; speedup 1.0000x reference)
//
#include <hip/hip_runtime.h>
#include <hip/hip_bf16.h>

#define BATCH 16384
#define TSTEPS 101
#define HDIM 512
#define GDIM 2048  // 4*H

typedef __attribute__((ext_vector_type(8))) short s16x8;
typedef __attribute__((ext_vector_type(4))) float f32x4;

__device__ __forceinline__ float sigm(float x){ return 1.0f/(1.0f + __expf(-x)); }
__device__ __forceinline__ float tanhx(float x){ float e=__expf(2.0f*x); return 1.0f - 2.0f/(e+1.0f); }

__device__ __forceinline__ void gload16(const void* g, void* l){
  __builtin_amdgcn_global_load_lds((const __attribute__((address_space(1))) unsigned int*)g,
                                   (__attribute__((address_space(3))) unsigned int*)l, 16, 0, 0);
}

// gates = hin @ W_hh^T (+ x_t @ W_ih^T + b), then LSTM cell update.
// 1024 blocks XCD-chunked: 64 row-panels (256 rows) x 16 col-blocks (32 h-cols, all 4 gates).
// A (h rows): direct global->VGPR frags, double-buffered in regs (no LDS, no barrier coupling).
// B (W_hh): LDS double-buffered, XOR-swizzled; one __syncthreads per K-tile.
__global__ __launch_bounds__(256, 2) void lstm_step(
    const __hip_bfloat16* __restrict__ hin,
    __hip_bfloat16* __restrict__ hout,
    float* __restrict__ cbuf,
    const float* __restrict__ bx,
    const float* __restrict__ Wih,
    const float* __restrict__ bcomb,
    const __hip_bfloat16* __restrict__ wbf,
    int t, int skipmm)
{
  __shared__ short sB[2][128*64];   // 4 gates x 32 cols of W_hh x 64 k, swizzled
  const int tid = threadIdx.x;
  const int l = tid & 63, w = tid >> 6;
  const int lr = l & 15, lk = l >> 4;

  const int orig = blockIdx.x;
  const int swz = (orig & 7)*128 + (orig >> 3);
  const int m0 = (swz >> 4) * 256;       // row-panel
  const int j0 = (swz & 15) * 32;        // per-gate col offset

  f32x4 acc[4][4][2] = {};  // [gate][m(4x16 rows)][n(2x16 cols)]

#define COMPUTE(AR, BUF)                                                        \
  do {                                                                          \
    _Pragma("unroll")                                                           \
    for (int kk = 0; kk < 2; ++kk){                                             \
      _Pragma("unroll")                                                         \
      for (int g = 0; g < 4; ++g){                                              \
        _Pragma("unroll")                                                       \
        for (int n = 0; n < 2; ++n){                                            \
          int rB = g*32 + n*16 + lr;                                            \
          int slot = rB*8 + ((kk*4 + lk) ^ (rB & 7));                           \
          s16x8 bv = *(const s16x8*)&sB[BUF][slot*8];                           \
          _Pragma("unroll")                                                     \
          for (int m = 0; m < 4; ++m)                                           \
            acc[g][m][n] = __builtin_amdgcn_mfma_f32_16x16x32_bf16(AR[m*2+kk], bv, acc[g][m][n], 0, 0, 0); \
        }                                                                       \
      }                                                                         \
    }                                                                           \
  } while(0)

  if (!skipmm){
    // thread-constant staging addresses for B (4 x 16B chunks/thread)
    int bch[4]; const __hip_bfloat16* bsrc[4];
    #pragma unroll
    for (int i = 0; i < 4; ++i){
      int cch = i*256 + tid;
      int r = cch >> 3, kc = cch & 7;
      int kcs = kc ^ (r & 7);
      bch[i] = cch*8;
      bsrc[i] = wbf + (size_t)((r >> 5)*HDIM + j0 + (r & 31))*HDIM + kcs*8;
    }
    // per-wave A row base pointers (4 m-frags x 16 rows)
    const __hip_bfloat16* arow[4];
    #pragma unroll
    for (int m = 0; m < 4; ++m)
      arow[m] = hin + (size_t)(m0 + w*64 + m*16 + lr)*HDIM + lk*8;

    s16x8 aE[8], aO[8];
    // prologue: stage B(k-tile 0) -> buf0, load A(0) -> aE
    #pragma unroll
    for (int i = 0; i < 4; ++i) gload16(bsrc[i], &sB[0][bch[i]]);
    #pragma unroll
    for (int m = 0; m < 4; ++m){
      aE[m*2+0] = *(const s16x8*)(arow[m]);
      aE[m*2+1] = *(const s16x8*)(arow[m] + 32);
    }
    __syncthreads();

    #pragma unroll
    for (int kt2 = 0; kt2 < 4; ++kt2){
      const int ko = kt2*2 + 1;
      {  // prefetch K-tile ko -> buf1 / aO
        const int k0 = ko*64;
        #pragma unroll
        for (int i = 0; i < 4; ++i) gload16(bsrc[i] + k0, &sB[1][bch[i]]);
        #pragma unroll
        for (int m = 0; m < 4; ++m){
          aO[m*2+0] = *(const s16x8*)(arow[m] + k0);
          aO[m*2+1] = *(const s16x8*)(arow[m] + k0 + 32);
        }
      }
      COMPUTE(aE, 0);
      __syncthreads();
      if (ko < 7){  // prefetch K-tile ko+1 -> buf0 / aE
        const int k0 = (ko+1)*64;
        #pragma unroll
        for (int i = 0; i < 4; ++i) gload16(bsrc[i] + k0, &sB[0][bch[i]]);
        #pragma unroll
        for (int m = 0; m < 4; ++m){
          aE[m*2+0] = *(const s16x8*)(arow[m] + k0);
          aE[m*2+1] = *(const s16x8*)(arow[m] + k0 + 32);
        }
      }
      COMPUTE(aO, 1);
      __syncthreads();
    }
  }

  // Epilogue: add x-projection + bias, apply cell update.
  // C/D mapping (m89): col = lane&15, row = (lane>>4)*4 + reg.
  float4 wv[4][2]; float bc[4][2];
  #pragma unroll
  for (int g = 0; g < 4; ++g){
    #pragma unroll
    for (int n = 0; n < 2; ++n){
      int col = j0 + n*16 + lr;
      int grow = g*HDIM + col;
      wv[g][n] = *(const float4*)(Wih + (size_t)grow*4);
      bc[g][n] = bcomb[grow];
    }
  }
  #pragma unroll
  for (int m = 0; m < 4; ++m){
    #pragma unroll
    for (int rg = 0; rg < 4; ++rg){
      int r = m0 + w*64 + m*16 + lk*4 + rg;
      float4 xv = *(const float4*)(bx + ((size_t)r*TSTEPS + t)*4);
      #pragma unroll
      for (int n = 0; n < 2; ++n){
        int col = j0 + n*16 + lr;
        float pi = acc[0][m][n][rg] + bc[0][n] + xv.x*wv[0][n].x + xv.y*wv[0][n].y + xv.z*wv[0][n].z + xv.w*wv[0][n].w;
        float pf = acc[1][m][n][rg] + bc[1][n] + xv.x*wv[1][n].x + xv.y*wv[1][n].y + xv.z*wv[1][n].z + xv.w*wv[1][n].w;
        float pg = acc[2][m][n][rg] + bc[2][n] + xv.x*wv[2][n].x + xv.y*wv[2][n].y + xv.z*wv[2][n].z + xv.w*wv[2][n].w;
        float po = acc[3][m][n][rg] + bc[3][n] + xv.x*wv[3][n].x + xv.y*wv[3][n].y + xv.z*wv[3][n].z + xv.w*wv[3][n].w;
        float iv = sigm(pi), fv = sigm(pf), gv = tanhx(pg), ov = sigm(po);
        size_t idx = (size_t)r*HDIM + col;
        float cn = fv*cbuf[idx] + iv*gv;
        cbuf[idx] = cn;
        hout[idx] = __float2bfloat16(ov*tanhx(cn));
      }
    }
  }
#undef COMPUTE
}

__global__ void prep(const float* __restrict__ Whh, const float* __restrict__ W1,
                     const float* __restrict__ bih, const float* __restrict__ bhh,
                     __hip_bfloat16* __restrict__ wbf, __hip_bfloat16* __restrict__ w1bf,
                     float* __restrict__ bcomb){
  int i = blockIdx.x*256 + threadIdx.x;
  if (i < GDIM*HDIM) wbf[i] = __float2bfloat16(Whh[i]);
  if (i < HDIM*HDIM) w1bf[i] = __float2bfloat16(W1[i]);
  if (i < GDIM) bcomb[i] = bih[i] + bhh[i];
}

// x = relu(hT @ W1^T + b1), bf16 MFMA, fp32 out. Block 128x128, wave 32x128.
__global__ __launch_bounds__(256) void mlp1(const __hip_bfloat16* __restrict__ hT,
                                            const __hip_bfloat16* __restrict__ w1bf,
                                            const float* __restrict__ b1, float* __restrict__ xout){
  __shared__ short sA[128*64];
  __shared__ short sB[128*64];
  const int tid = threadIdx.x;
  const int l = tid & 63, w = tid >> 6;
  const int lr = l & 15, lk = l >> 4;
  const int r0 = blockIdx.x * 128, c0 = blockIdx.y * 128;

  f32x4 acc[2][8] = {};
  for (int k0 = 0; k0 < HDIM; k0 += 64){
    __syncthreads();
    #pragma unroll
    for (int i = 0; i < 4; ++i){
      int cch = i*256 + tid;
      int row = cch >> 3, kc = cch & 7;
      int kcs = kc ^ (row & 7);
      gload16(hT + (size_t)(r0 + row)*HDIM + k0 + kcs*8, &sA[cch*8]);
    }
    #pragma unroll
    for (int i = 0; i < 4; ++i){
      int cch = i*256 + tid;
      int row = cch >> 3, kc = cch & 7;
      int kcs = kc ^ (row & 7);
      gload16(w1bf + (size_t)(c0 + row)*HDIM + k0 + kcs*8, &sB[cch*8]);
    }
    __syncthreads();
    #pragma unroll
    for (int kk = 0; kk < 2; ++kk){
      s16x8 av[2];
      #pragma unroll
      for (int m = 0; m < 2; ++m){
        int row = w*32 + m*16 + lr;
        int slot = row*8 + ((kk*4 + lk) ^ (row & 7));
        av[m] = *(const s16x8*)&sA[slot*8];
      }
      #pragma unroll
      for (int n = 0; n < 8; ++n){
        int rB = n*16 + lr;
        int slot = rB*8 + ((kk*4 + lk) ^ (rB & 7));
        s16x8 bv = *(const s16x8*)&sB[slot*8];
        #pragma unroll
        for (int m = 0; m < 2; ++m)
          acc[m][n] = __builtin_amdgcn_mfma_f32_16x16x32_bf16(av[m], bv, acc[m][n], 0, 0, 0);
      }
    }
  }
  #pragma unroll
  for (int m = 0; m < 2; ++m){
    #pragma unroll
    for (int rg = 0; rg < 4; ++rg){
      int r = r0 + w*32 + m*16 + lk*4 + rg;
      #pragma unroll
      for (int n = 0; n < 8; ++n){
        int c = c0 + n*16 + lr;
        float v = acc[m][n][rg] + b1[c];
        xout[(size_t)r*HDIM + c] = v > 0.f ? v : 0.f;
      }
    }
  }
}

// out[b] = x[b,:] . W2[0:512] + a[b]*W2[512] + b2 ; one wave per row
__global__ __launch_bounds__(256) void mlp2(const float* __restrict__ x, const float* __restrict__ a,
                                            const float* __restrict__ W2, const float* __restrict__ b2,
                                            float* __restrict__ out){
  const int wi = threadIdx.x >> 6, l = threadIdx.x & 63;
  const int b = blockIdx.x*4 + wi;
  const float* xr = x + (size_t)b*HDIM;
  float4 v0 = *(const float4*)(xr + l*8);
  float4 v1 = *(const float4*)(xr + l*8 + 4);
  float4 w0 = *(const float4*)(W2 + l*8);
  float4 w1 = *(const float4*)(W2 + l*8 + 4);
  float s = v0.x*w0.x + v0.y*w0.y + v0.z*w0.z + v0.w*w0.w
          + v1.x*w1.x + v1.y*w1.y + v1.z*w1.z + v1.w*w1.w;
  #pragma unroll
  for (int off = 32; off > 0; off >>= 1) s += __shfl_down(s, off);
  if (l == 0) out[b] = s + a[b]*W2[HDIM] + b2[0];
}

extern "C" void kernel_launch(void* const* d_in, const int* in_sizes, int n_in,
                              void* d_out, int out_size, void* d_ws, size_t ws_size,
                              hipStream_t stream){
  const float* bx  = (const float*)d_in[0];
  const float* ba  = (const float*)d_in[1];
  const float* Wih = (const float*)d_in[2];
  const float* Whh = (const float*)d_in[3];
  const float* bih = (const float*)d_in[4];
  const float* bhh = (const float*)d_in[5];
  const float* W1  = (const float*)d_in[6];
  const float* b1  = (const float*)d_in[7];
  const float* W2  = (const float*)d_in[8];
  const float* b2  = (const float*)d_in[9];
  float* out = (float*)d_out;

  char* ws = (char*)d_ws;
  __hip_bfloat16* wbf   = (__hip_bfloat16*)(ws);              // 2 MB
  __hip_bfloat16* w1bf  = (__hip_bfloat16*)(ws + 2097152);    // 512 KB
  float*          bcomb = (float*)(ws + 2621440);             // 8 KB
  __hip_bfloat16* hb0   = (__hip_bfloat16*)(ws + 2629632);    // 16 MB
  __hip_bfloat16* hb1   = (__hip_bfloat16*)(ws + 19406848);   // 16 MB
  float*          cbuf  = (float*)(ws + 36184064);            // 32 MB (end ~66.5 MB)
  float*          xmlp  = cbuf;  // c dead after last step; reuse for MLP activations

  prep<<<4096, 256, 0, stream>>>(Whh, W1, bih, bhh, wbf, w1bf, bcomb);
  hipMemsetAsync(cbuf, 0, (size_t)BATCH*HDIM*sizeof(float), stream);

  for (int t = 0; t < TSTEPS; ++t){
    const __hip_bfloat16* hin = (t & 1) ? hb1 : hb0;
    __hip_bfloat16*      hout = (t & 1) ? hb0 : hb1;
    lstm_step<<<1024, 256, 0, stream>>>(hin, hout, cbuf, bx, Wih, bcomb, wbf,
                                        t, (t == 0) ? 1 : 0);
  }
  // t=100 wrote hout = hb1
  mlp1<<<dim3(128, 4), 256, 0, stream>>>(hb1, w1bf, b1, xmlp);
  mlp2<<<4096, 256, 0, stream>>>(xmlp, ba, W2, b2, out);
}

// Round 4
// 6234.972 us; speedup vs baseline: 1.0512x; 1.0512x over previous
//
#include <hip/hip_runtime.h>
#include <hip/hip_bf16.h>

#define BATCH 16384
#define TSTEPS 101
#define HDIM 512
#define GDIM 2048  // 4*H

typedef __attribute__((ext_vector_type(8))) short s16x8;
typedef __attribute__((ext_vector_type(4))) float f32x4;

__device__ __forceinline__ float sigm(float x){ return 1.0f/(1.0f + __expf(-x)); }
__device__ __forceinline__ float tanhx(float x){ float e=__expf(2.0f*x); return 1.0f - 2.0f/(e+1.0f); }

__device__ __forceinline__ void gload16(const void* g, void* l){
  __builtin_amdgcn_global_load_lds((const __attribute__((address_space(1))) unsigned int*)g,
                                   (__attribute__((address_space(3))) unsigned int*)l, 16, 0, 0);
}

// gates = hin @ W_hh^T (+ x_t @ W_ih^T + b), then LSTM cell update.
// 1024 blocks XCD-chunked: 64 row-panels (256 rows) x 16 col-blocks (32 h-cols, all 4 gates).
// K-tile 32, triple-buffered A+B in LDS, stage-early distance 2, counted vmcnt(6),
// one raw s_barrier per tile (no vmcnt(0) drain in steady state).
// LDS 64B rows; 2-way-free swizzle: chunk slot = (row&1)*4 + ((lk + (row>>1))&3),
// applied on the GLOBAL source (LDS linear) and mirrored on the read side.
__global__ __launch_bounds__(256, 2) void lstm_step(
    const __hip_bfloat16* __restrict__ hin,
    __hip_bfloat16* __restrict__ hout,
    float* __restrict__ cbuf,
    const float* __restrict__ bx,
    const float* __restrict__ Wih,
    const float* __restrict__ bcomb,
    const __hip_bfloat16* __restrict__ wbf,
    int t, int skipmm)
{
  __shared__ short sA[3*8192];   // 3 bufs x 256 rows x 32 k
  __shared__ short sB[3*4096];   // 3 bufs x 128 gate-rows x 32 k
  const int tid = threadIdx.x;
  const int l = tid & 63, w = tid >> 6;
  const int lr = l & 15, lk = l >> 4;

  const int orig = blockIdx.x;
  const int swz = (orig & 7)*128 + (orig >> 3);
  const int m0 = (swz >> 4) * 256;       // row-panel
  const int j0 = (swz & 15) * 32;        // per-gate col offset

  f32x4 acc[4][4][2] = {};  // [gate][m(4x16 rows)][n(2x16 cols)]

  if (!skipmm){
    // staging: per-thread 4 A-chunks + 2 B-chunks of 16B. LDS linear, source carries
    // the inverse swizzle: chunk c -> pair p=c>>3, slot s=c&7, row=2p+(s>>2), lk=((s&3)-p)&3.
    const __hip_bfloat16* asrc[4]; int adst[4];
    #pragma unroll
    for (int i = 0; i < 4; ++i){
      int c = i*256 + tid;
      int p = c >> 3, s = c & 7;
      int row = p*2 + (s >> 2);
      int lkg = ((s & 3) + 4 - (p & 3)) & 3;
      asrc[i] = hin + (size_t)(m0 + row)*HDIM + lkg*8;
      adst[i] = c*8;
    }
    const __hip_bfloat16* bsrc[2]; int bdst[2];
    #pragma unroll
    for (int i = 0; i < 2; ++i){
      int c = i*256 + tid;
      int p = c >> 3, s = c & 7;
      int grow = p*2 + (s >> 2);
      int lkg = ((s & 3) + 4 - (p & 3)) & 3;
      int wrow = (grow >> 5)*HDIM + j0 + (grow & 31);
      bsrc[i] = wbf + (size_t)wrow*HDIM + lkg*8;
      bdst[i] = c*8;
    }
    // read bases (bytes): row r, slot = (r&1)*4 + ((lk + (r>>1))&3); the (&3) term is
    // invariant under r += multiples of 4, so one base covers all m/g/n via literals.
    const int raddA = (w*32 + (lr >> 1))*128 + ((lr & 1) << 6) + (((lk + (lr >> 1)) & 3) << 4);
    const int raddB = ((lr >> 1))*128 + ((lr & 1) << 6) + (((lk + (lr >> 1)) & 3) << 4);
    const short* pA = (const short*)((const char*)sA + raddA);
    const short* pB = (const short*)((const char*)sB + raddB);

#define STAGE(BI, KT) do{                                                        \
    _Pragma("unroll")                                                            \
    for (int i = 0; i < 2; ++i) gload16(bsrc[i] + (KT)*32, &sB[(BI)*4096 + bdst[i]]); \
    _Pragma("unroll")                                                            \
    for (int i = 0; i < 4; ++i) gload16(asrc[i] + (KT)*32, &sA[(BI)*8192 + adst[i]]); \
  }while(0)

#define COMPUTE(BI) do{                                                          \
    s16x8 av[4];                                                                 \
    _Pragma("unroll")                                                            \
    for (int m = 0; m < 4; ++m) av[m] = *(const s16x8*)(pA + (BI)*8192 + m*512); \
    __builtin_amdgcn_s_setprio(1);                                               \
    _Pragma("unroll")                                                            \
    for (int g = 0; g < 4; ++g){                                                 \
      _Pragma("unroll")                                                          \
      for (int n = 0; n < 2; ++n){                                               \
        s16x8 bv = *(const s16x8*)(pB + (BI)*4096 + g*1024 + n*512);             \
        _Pragma("unroll")                                                        \
        for (int m = 0; m < 4; ++m)                                              \
          acc[g][m][n] = __builtin_amdgcn_mfma_f32_16x16x32_bf16(av[m], bv, acc[g][m][n], 0, 0, 0); \
      }                                                                          \
    }                                                                            \
    __builtin_amdgcn_s_setprio(0);                                               \
  }while(0)

    // prologue: tiles 0 and 1 in flight; wait only for tile 0.
    STAGE(0, 0);
    STAGE(1, 1);
    asm volatile("s_waitcnt vmcnt(6)" ::: "memory");
    __builtin_amdgcn_s_barrier();
    __builtin_amdgcn_sched_barrier(0);

    #pragma unroll
    for (int kt = 0; kt < 16; ++kt){
      if (kt < 14) STAGE((kt + 2) % 3, kt + 2);
      __builtin_amdgcn_sched_barrier(0);
      COMPUTE(kt % 3);
      if (kt <= 13) asm volatile("s_waitcnt vmcnt(6)" ::: "memory");
      else          asm volatile("s_waitcnt vmcnt(0)" ::: "memory");
      __builtin_amdgcn_s_barrier();
      __builtin_amdgcn_sched_barrier(0);
    }
#undef STAGE
#undef COMPUTE
  }

  // Epilogue: add x-projection + bias, apply cell update.
  // C/D mapping (m89): col = lane&15, row = (lane>>4)*4 + reg.
  float4 wv[4][2]; float bc[4][2];
  #pragma unroll
  for (int g = 0; g < 4; ++g){
    #pragma unroll
    for (int n = 0; n < 2; ++n){
      int col = j0 + n*16 + lr;
      int grow = g*HDIM + col;
      wv[g][n] = *(const float4*)(Wih + (size_t)grow*4);
      bc[g][n] = bcomb[grow];
    }
  }
  #pragma unroll
  for (int m = 0; m < 4; ++m){
    #pragma unroll
    for (int rg = 0; rg < 4; ++rg){
      int r = m0 + w*64 + m*16 + lk*4 + rg;
      float4 xv = *(const float4*)(bx + ((size_t)r*TSTEPS + t)*4);
      #pragma unroll
      for (int n = 0; n < 2; ++n){
        int col = j0 + n*16 + lr;
        float pi = acc[0][m][n][rg] + bc[0][n] + xv.x*wv[0][n].x + xv.y*wv[0][n].y + xv.z*wv[0][n].z + xv.w*wv[0][n].w;
        float pf = acc[1][m][n][rg] + bc[1][n] + xv.x*wv[1][n].x + xv.y*wv[1][n].y + xv.z*wv[1][n].z + xv.w*wv[1][n].w;
        float pg = acc[2][m][n][rg] + bc[2][n] + xv.x*wv[2][n].x + xv.y*wv[2][n].y + xv.z*wv[2][n].z + xv.w*wv[2][n].w;
        float po = acc[3][m][n][rg] + bc[3][n] + xv.x*wv[3][n].x + xv.y*wv[3][n].y + xv.z*wv[3][n].z + xv.w*wv[3][n].w;
        float iv = sigm(pi), fv = sigm(pf), gv = tanhx(pg), ov = sigm(po);
        size_t idx = (size_t)r*HDIM + col;
        float cn = fv*cbuf[idx] + iv*gv;
        cbuf[idx] = cn;
        hout[idx] = __float2bfloat16(ov*tanhx(cn));
      }
    }
  }
}

__global__ void prep(const float* __restrict__ Whh, const float* __restrict__ W1,
                     const float* __restrict__ bih, const float* __restrict__ bhh,
                     __hip_bfloat16* __restrict__ wbf, __hip_bfloat16* __restrict__ w1bf,
                     float* __restrict__ bcomb){
  int i = blockIdx.x*256 + threadIdx.x;
  if (i < GDIM*HDIM) wbf[i] = __float2bfloat16(Whh[i]);
  if (i < HDIM*HDIM) w1bf[i] = __float2bfloat16(W1[i]);
  if (i < GDIM) bcomb[i] = bih[i] + bhh[i];
}

// x = relu(hT @ W1^T + b1), bf16 MFMA, fp32 out. Block 128x128, wave 32x128.
__global__ __launch_bounds__(256) void mlp1(const __hip_bfloat16* __restrict__ hT,
                                            const __hip_bfloat16* __restrict__ w1bf,
                                            const float* __restrict__ b1, float* __restrict__ xout){
  __shared__ short sA[128*64];
  __shared__ short sB[128*64];
  const int tid = threadIdx.x;
  const int l = tid & 63, w = tid >> 6;
  const int lr = l & 15, lk = l >> 4;
  const int r0 = blockIdx.x * 128, c0 = blockIdx.y * 128;

  f32x4 acc[2][8] = {};
  for (int k0 = 0; k0 < HDIM; k0 += 64){
    __syncthreads();
    #pragma unroll
    for (int i = 0; i < 4; ++i){
      int cch = i*256 + tid;
      int row = cch >> 3, kc = cch & 7;
      int kcs = kc ^ (row & 7);
      gload16(hT + (size_t)(r0 + row)*HDIM + k0 + kcs*8, &sA[cch*8]);
    }
    #pragma unroll
    for (int i = 0; i < 4; ++i){
      int cch = i*256 + tid;
      int row = cch >> 3, kc = cch & 7;
      int kcs = kc ^ (row & 7);
      gload16(w1bf + (size_t)(c0 + row)*HDIM + k0 + kcs*8, &sB[cch*8]);
    }
    __syncthreads();
    #pragma unroll
    for (int kk = 0; kk < 2; ++kk){
      s16x8 av[2];
      #pragma unroll
      for (int m = 0; m < 2; ++m){
        int row = w*32 + m*16 + lr;
        int slot = row*8 + ((kk*4 + lk) ^ (row & 7));
        av[m] = *(const s16x8*)&sA[slot*8];
      }
      #pragma unroll
      for (int n = 0; n < 8; ++n){
        int rB = n*16 + lr;
        int slot = rB*8 + ((kk*4 + lk) ^ (rB & 7));
        s16x8 bv = *(const s16x8*)&sB[slot*8];
        #pragma unroll
        for (int m = 0; m < 2; ++m)
          acc[m][n] = __builtin_amdgcn_mfma_f32_16x16x32_bf16(av[m], bv, acc[m][n], 0, 0, 0);
      }
    }
  }
  #pragma unroll
  for (int m = 0; m < 2; ++m){
    #pragma unroll
    for (int rg = 0; rg < 4; ++rg){
      int r = r0 + w*32 + m*16 + lk*4 + rg;
      #pragma unroll
      for (int n = 0; n < 8; ++n){
        int c = c0 + n*16 + lr;
        float v = acc[m][n][rg] + b1[c];
        xout[(size_t)r*HDIM + c] = v > 0.f ? v : 0.f;
      }
    }
  }
}

// out[b] = x[b,:] . W2[0:512] + a[b]*W2[512] + b2 ; one wave per row
__global__ __launch_bounds__(256) void mlp2(const float* __restrict__ x, const float* __restrict__ a,
                                            const float* __restrict__ W2, const float* __restrict__ b2,
                                            float* __restrict__ out){
  const int wi = threadIdx.x >> 6, l = threadIdx.x & 63;
  const int b = blockIdx.x*4 + wi;
  const float* xr = x + (size_t)b*HDIM;
  float4 v0 = *(const float4*)(xr + l*8);
  float4 v1 = *(const float4*)(xr + l*8 + 4);
  float4 w0 = *(const float4*)(W2 + l*8);
  float4 w1 = *(const float4*)(W2 + l*8 + 4);
  float s = v0.x*w0.x + v0.y*w0.y + v0.z*w0.z + v0.w*w0.w
          + v1.x*w1.x + v1.y*w1.y + v1.z*w1.z + v1.w*w1.w;
  #pragma unroll
  for (int off = 32; off > 0; off >>= 1) s += __shfl_down(s, off);
  if (l == 0) out[b] = s + a[b]*W2[HDIM] + b2[0];
}

extern "C" void kernel_launch(void* const* d_in, const int* in_sizes, int n_in,
                              void* d_out, int out_size, void* d_ws, size_t ws_size,
                              hipStream_t stream){
  const float* bx  = (const float*)d_in[0];
  const float* ba  = (const float*)d_in[1];
  const float* Wih = (const float*)d_in[2];
  const float* Whh = (const float*)d_in[3];
  const float* bih = (const float*)d_in[4];
  const float* bhh = (const float*)d_in[5];
  const float* W1  = (const float*)d_in[6];
  const float* b1  = (const float*)d_in[7];
  const float* W2  = (const float*)d_in[8];
  const float* b2  = (const float*)d_in[9];
  float* out = (float*)d_out;

  char* ws = (char*)d_ws;
  __hip_bfloat16* wbf   = (__hip_bfloat16*)(ws);              // 2 MB
  __hip_bfloat16* w1bf  = (__hip_bfloat16*)(ws + 2097152);    // 512 KB
  float*          bcomb = (float*)(ws + 2621440);             // 8 KB
  __hip_bfloat16* hb0   = (__hip_bfloat16*)(ws + 2629632);    // 16 MB
  __hip_bfloat16* hb1   = (__hip_bfloat16*)(ws + 19406848);   // 16 MB
  float*          cbuf  = (float*)(ws + 36184064);            // 32 MB (end ~66.5 MB)
  float*          xmlp  = cbuf;  // c dead after last step; reuse for MLP activations

  prep<<<4096, 256, 0, stream>>>(Whh, W1, bih, bhh, wbf, w1bf, bcomb);
  hipMemsetAsync(cbuf, 0, (size_t)BATCH*HDIM*sizeof(float), stream);

  for (int t = 0; t < TSTEPS; ++t){
    const __hip_bfloat16* hin = (t & 1) ? hb1 : hb0;
    __hip_bfloat16*      hout = (t & 1) ? hb0 : hb1;
    lstm_step<<<1024, 256, 0, stream>>>(hin, hout, cbuf, bx, Wih, bcomb, wbf,
                                        t, (t == 0) ? 1 : 0);
  }
  // t=100 wrote hout = hb1
  mlp1<<<dim3(128, 4), 256, 0, stream>>>(hb1, w1bf, b1, xmlp);
  mlp2<<<4096, 256, 0, stream>>>(xmlp, ba, W2, b2, out);
}